// Round 1
// baseline (204.923 us; speedup 1.0000x reference)
//
#include <hip/hip_runtime.h>

// RelScaleAttend: b=4, 16 heads, s=1024 (32x32 img), d=64. Single fused kernel.
// Block = (h-pair, bh): 64 queries, 4 waves x 16 queries. K-tile = 64 keys.
// Phase 0: exact fp32 rel tables (x log2e) + per-query max-bound M into LDS.
// Phase 1: flash loop, bf16 MFMA 16x16x32, fp32 accum, STATIC-max softmax:
//   p = exp2(qk*SCALE2 + relh2 + relw2 - M[q]); M = max_kh relh2 + max_kw relw2
//   bounds the true row max within +-|qk|/8*log2e (every (kh,kw) key exists),
//   so no running max / rescale / per-tile reductions are needed (exact math).
// K/V for tile kt+1 are prefetched into registers during tile kt's compute.
//
// LDS budget (36864 B -> 4 blocks/CU, whole 1024-block grid co-resident):
//   RelH 64x34 f32 (read every tile, persistent) + MH[4][64]
//   arena (27136 B), phase0:  Ql 64x68 f32 [0,17408) | RelW 64x34 f32 [17408,26112)
//          phase1:  Kl 64x72 bf16 [0,9216) | Vl 64x68 [9216,17920) | Pl 4x16x72 [17920,27136)
//   RelW dies at the loop's first __syncthreads (folded into rwm registers
//   pre-loop), exactly where Kl/Vl/Pl come alive -> aliasing is safe.

#define SCALE2 0.18033688f   // 0.125 * log2(e)
#define LOG2E  1.44269504f

typedef float  f32x4  __attribute__((ext_vector_type(4)));
typedef __bf16 bf16x8 __attribute__((ext_vector_type(8)));
typedef __bf16 bf16x4 __attribute__((ext_vector_type(4)));
typedef __bf16 bf16x2 __attribute__((ext_vector_type(2)));

__global__ __launch_bounds__(256, 4) void attn(
        const float* __restrict__ qg, const float* __restrict__ kg,
        const float* __restrict__ vg,
        const float* __restrict__ rph, const float* __restrict__ rpw,
        float* __restrict__ outg) {
    __shared__ float RelH[64 * 34];
    __shared__ float MH[4 * 64];
    __shared__ __align__(16) char arena[27136];
    float*  Ql   = (float*)arena;                 // phase0: 64*68*4 = 17408 B
    float*  RelW = (float*)(arena + 17408);       // phase0: 64*34*4 =  8704 B
    __bf16* Kl = (__bf16*)arena;                  // phase1: 64*72*2 = 9216 B
    __bf16* Vl = Kl + 64 * 72;                    // phase1: 64*68*2 = 8704 B
    __bf16* Pl = Vl + 64 * 68;                    // phase1: 4*16*72*2 = 9216 B

    const int tid  = threadIdx.x;
    const int w    = tid >> 6, lane = tid & 63;
    const int quad = lane >> 4, n16 = lane & 15;
    const int hp = blockIdx.x, bh = blockIdx.y;
    const int bb = bh >> 4, nh = bh & 15;
    const int h0 = hp << 1;
    const int base = bb * 1048576 + nh * 64;   // per-head element base
    const int sq0  = h0 * 32;                  // first query row of block

    // ---- stage Q rows (fp32) into LDS, coalesced b128 ----
    {
        int r0 = tid >> 4, c0 = (tid & 15) << 2;
#pragma unroll
        for (int k = 0; k < 4; ++k) {
            int row = k * 16 + r0;
            f32x4 v = *(const f32x4*)(qg + base + (sq0 + row) * 1024 + c0);
            *(f32x4*)&Ql[row * 68 + c0] = v;
        }
    }
    __syncthreads();

    // ---- phase 0: rel tables (x log2e) + per-slot max ----
    {
        int ql = tid & 63, slot = tid >> 6;
        int isw = slot >> 1, khb = (slot & 1) << 4;
        int hh = h0 + (ql >> 5), wl = ql & 31;
        int row0 = (isw ? wl : hh) + 31 - khb;      // row_j = row0 - j
        const float* tp = (isw ? rpw : rph) + row0 * 64;
        const float* qrow = &Ql[ql * 68];
        float acc[16];
#pragma unroll
        for (int j = 0; j < 16; ++j) acc[j] = 0.f;
#pragma unroll 4
        for (int cq = 0; cq < 16; ++cq) {
            f32x4 qv = *(const f32x4*)(qrow + cq * 4);
#pragma unroll
            for (int j = 0; j < 16; ++j) {
                f32x4 tv = *(const f32x4*)(tp - j * 64 + cq * 4);
                acc[j] += qv.x * tv.x + qv.y * tv.y + qv.z * tv.z + qv.w * tv.w;
            }
        }
        float* dst = (isw ? RelW : RelH) + ql * 34 + khb;
        float hmax = -1e30f;
#pragma unroll
        for (int j = 0; j < 16; ++j) {
            float v = acc[j] * LOG2E;
            dst[j] = v;
            hmax = fmaxf(hmax, v);
        }
        MH[slot * 64 + ql] = hmax;
    }

    // ---- Q A-fragments from Ql: A[m=n16][k=quad*8+j], query = w*16+n16 ----
    const int qla = w * 16 + n16;
    bf16x8 qf[2];
#pragma unroll
    for (int ch = 0; ch < 2; ++ch) {
        const float* qp = &Ql[qla * 68 + ch * 32 + quad * 8];
        f32x4 a = ((const f32x4*)qp)[0];
        f32x4 b = ((const f32x4*)qp)[1];
        bf16x8 t;
        t[0] = (__bf16)a.x; t[1] = (__bf16)a.y; t[2] = (__bf16)a.z; t[3] = (__bf16)a.w;
        t[4] = (__bf16)b.x; t[5] = (__bf16)b.y; t[6] = (__bf16)b.z; t[7] = (__bf16)b.w;
        qf[ch] = t;
    }
    __syncthreads();   // Rel/MH ready; Ql consumed into qf

    // C/D rows this lane owns: local query = w*16 + quad*4 + r
    int qlr[4];
#pragma unroll
    for (int r = 0; r < 4; ++r) qlr[r] = w * 16 + quad * 4 + r;

    // per-row static max M and (rel_w - M); rel_w is tile-invariant.
    // RelW is consumed into registers HERE; it is dead after the loop's
    // first __syncthreads (which precedes the first Kl/Vl store).
    float rwm[4][2];
#pragma unroll
    for (int r = 0; r < 4; ++r) {
        int q = qlr[r];
        float M = fmaxf(MH[q], MH[64 + q]) + fmaxf(MH[128 + q], MH[192 + q]);
        rwm[r][0] = RelW[q * 34 + n16] - M;
        rwm[r][1] = RelW[q * 34 + 16 + n16] - M;
    }

    float lr[4] = {0.f, 0.f, 0.f, 0.f};
    f32x4 oc[4];
#pragma unroll
    for (int i = 0; i < 4; ++i) oc[i] = (f32x4){0.f, 0.f, 0.f, 0.f};

    const int krow = tid >> 3, kc0 = (tid & 7) << 3;   // K staging coords
    const int vc = tid & 63, vk0 = (tid >> 6) << 4;    // V staging coords
    const int pw = w * 1152;                           // per-wave P base

    // ---- register prefetch of tile 0 ----
    f32x4 ka[2], kb[2];
    float vv[16];
#pragma unroll
    for (int half = 0; half < 2; ++half) {
        const float* kp = kg + base + (krow + half * 32) * 1024 + kc0;
        ka[half] = ((const f32x4*)kp)[0];
        kb[half] = ((const f32x4*)kp)[1];
    }
#pragma unroll
    for (int j = 0; j < 16; ++j)
        vv[j] = vg[base + (vk0 + j) * 1024 + vc];

    for (int kt = 0; kt < 16; ++kt) {
        __syncthreads();   // previous iter's LDS reads done (also: RelW dead)
        // ---- store prefetched K tile (bf16, b128 writes) ----
#pragma unroll
        for (int half = 0; half < 2; ++half) {
            bf16x8 t;
            t[0] = (__bf16)ka[half].x; t[1] = (__bf16)ka[half].y;
            t[2] = (__bf16)ka[half].z; t[3] = (__bf16)ka[half].w;
            t[4] = (__bf16)kb[half].x; t[5] = (__bf16)kb[half].y;
            t[6] = (__bf16)kb[half].z; t[7] = (__bf16)kb[half].w;
            *(bf16x8*)&Kl[(krow + half * 32) * 72 + kc0] = t;
        }
        // ---- store prefetched V transposed: Vl[c][kk], packed pairs ----
#pragma unroll
        for (int j = 0; j < 8; ++j) {
            bf16x2 p; p[0] = (__bf16)vv[2 * j]; p[1] = (__bf16)vv[2 * j + 1];
            *(bf16x2*)&Vl[vc * 68 + vk0 + 2 * j] = p;
        }
        __syncthreads();

        // ---- issue global loads for tile kt+1 (overlap with compute) ----
        if (kt < 15) {
#pragma unroll
            for (int half = 0; half < 2; ++half) {
                const float* kp = kg + base + ((kt + 1) * 64 + krow + half * 32) * 1024 + kc0;
                ka[half] = ((const f32x4*)kp)[0];
                kb[half] = ((const f32x4*)kp)[1];
            }
#pragma unroll
            for (int j = 0; j < 16; ++j)
                vv[j] = vg[base + ((kt + 1) * 64 + vk0 + j) * 1024 + vc];
        }

        float rh[4][2];
#pragma unroll
        for (int r = 0; r < 4; ++r) {
            float2 t = *(const float2*)&RelH[qlr[r] * 34 + kt * 2];
            rh[r][0] = t.x; rh[r][1] = t.y;
        }

        // ---- S = Q K^T : 8 MFMAs ----
        f32x4 s[4];
#pragma unroll
        for (int g = 0; g < 4; ++g) s[g] = (f32x4){0.f, 0.f, 0.f, 0.f};
#pragma unroll
        for (int ch = 0; ch < 2; ++ch)
#pragma unroll
            for (int g = 0; g < 4; ++g) {
                bf16x8 kf = *(const bf16x8*)&Kl[(g * 16 + n16) * 72 + ch * 32 + quad * 8];
                s[g] = __builtin_amdgcn_mfma_f32_16x16x32_bf16(qf[ch], kf, s[g], 0, 0, 0);
            }

        // ---- static-max softmax: p = exp2(s*SCALE2 + rh + rw - M) ----
#pragma unroll
        for (int r = 0; r < 4; ++r) {
            float p0 = __builtin_amdgcn_exp2f(fmaf(s[0][r], SCALE2, rh[r][0] + rwm[r][0]));
            float p1 = __builtin_amdgcn_exp2f(fmaf(s[1][r], SCALE2, rh[r][0] + rwm[r][1]));
            float p2 = __builtin_amdgcn_exp2f(fmaf(s[2][r], SCALE2, rh[r][1] + rwm[r][0]));
            float p3 = __builtin_amdgcn_exp2f(fmaf(s[3][r], SCALE2, rh[r][1] + rwm[r][1]));
            lr[r] += (p0 + p1) + (p2 + p3);
            int pr = pw + (quad * 4 + r) * 72;
            Pl[pr + n16]      = (__bf16)p0;
            Pl[pr + 16 + n16] = (__bf16)p1;
            Pl[pr + 32 + n16] = (__bf16)p2;
            Pl[pr + 48 + n16] = (__bf16)p3;
        }

        // ---- O += P V ----
#pragma unroll
        for (int ko = 0; ko < 2; ++ko) {
            bf16x8 pf = *(const bf16x8*)&Pl[pw + n16 * 72 + ko * 32 + quad * 8];
#pragma unroll
            for (int cn = 0; cn < 4; ++cn) {
                const __bf16* vp = &Vl[(cn * 16 + n16) * 68 + ko * 32 + quad * 8];
                bf16x4 a = *(const bf16x4*)vp;
                bf16x4 b = *(const bf16x4*)(vp + 4);
                bf16x8 vf;
                vf[0] = a[0]; vf[1] = a[1]; vf[2] = a[2]; vf[3] = a[3];
                vf[4] = b[0]; vf[5] = b[1]; vf[6] = b[2]; vf[7] = b[3];
                oc[cn] = __builtin_amdgcn_mfma_f32_16x16x32_bf16(pf, vf, oc[cn], 0, 0, 0);
            }
        }
    }

    // ---- epilogue: one l-reduction across the 16-lane row group, store ----
#pragma unroll
    for (int r = 0; r < 4; ++r) {
        float l = lr[r];
        l += __shfl_xor(l, 1);
        l += __shfl_xor(l, 2);
        l += __shfl_xor(l, 4);
        l += __shfl_xor(l, 8);
        float inv = 1.f / l;
        int ob = base + (sq0 + qlr[r]) * 1024 + n16;
        outg[ob]      = oc[0][r] * inv;
        outg[ob + 16] = oc[1][r] * inv;
        outg[ob + 32] = oc[2][r] * inv;
        outg[ob + 48] = oc[3][r] * inv;
    }
}

extern "C" void kernel_launch(void* const* d_in, const int* in_sizes, int n_in,
                              void* d_out, int out_size, void* d_ws, size_t ws_size,
                              hipStream_t stream) {
    (void)in_sizes; (void)n_in; (void)out_size; (void)d_ws; (void)ws_size;
    const float* q   = (const float*)d_in[0];
    const float* k   = (const float*)d_in[1];
    const float* v   = (const float*)d_in[2];
    const float* rph = (const float*)d_in[3];
    const float* rpw = (const float*)d_in[4];
    dim3 g(16, 64);                      // (h-pair, bh)
    attn<<<g, 256, 0, stream>>>(q, k, v, rph, rpw, (float*)d_out);
}

// Round 2
// 199.643 us; speedup vs baseline: 1.0264x; 1.0264x over previous
//
#include <hip/hip_runtime.h>

// RelScaleAttend: b=4, 16 heads, s=1024 (32x32 img), d=64. Single fused kernel.
// Block = (h-pair, bh): 64 queries, 4 waves x 16 queries. K-tile = 64 keys.
// Phase 0: exact fp32 rel tables (x log2e) + per-query max-bound M into LDS.
// Phase 1: flash loop, bf16 MFMA 16x16x32, fp32 accum, STATIC-max softmax:
//   p = exp2(qk*SCALE2 + relh2 + relw2 - M[q]); M = max_kh relh2 + max_kw relw2
// K/V for tile kt+1 are prefetched into registers during tile kt's compute and
// stay IN FLIGHT across both barriers: loop barriers are raw s_barrier with
// lgkmcnt(0) only (no vmcnt drain). Hazard audit: every ds_read before a
// barrier is data-consumed (MFMA/VALU) pre-barrier, and lgkmcnt(0) covers all
// ds_writes; global loads have no cross-wave visibility requirement.
//
// XCD head-affinity swizzle: the 16 blocks sharing one head's K/V are mapped
// to the same XCD (linear-id mod 8 == head mod 8 under assumed round-robin
// dispatch) so K/V re-reads hit the XCD-local L2 instead of HBM.
//
// LDS budget (36864 B -> 4 blocks/CU, whole 1024-block grid co-resident):
//   RelH 64x34 f32 (persistent) + MH[4][64]
//   arena: phase0  Ql 64x68 f32 [0,17408) | RelW 64x34 f32 [17408,26112)
//          phase1  Kl 64x72 bf16 [0,9216) | Vl 64x68 [9216,17920) | Pl 4x16x72 [17920,27136)
//   RelW dies at the loop's first barrier (lgkmcnt(0) there guarantees the
//   rwm reads sampled LDS before Kl/Vl overwrite it).

#define SCALE2 0.18033688f   // 0.125 * log2(e)
#define LOG2E  1.44269504f

typedef float  f32x4  __attribute__((ext_vector_type(4)));
typedef __bf16 bf16x8 __attribute__((ext_vector_type(8)));
typedef __bf16 bf16x4 __attribute__((ext_vector_type(4)));
typedef __bf16 bf16x2 __attribute__((ext_vector_type(2)));

// Barrier with LDS-completion only; vmcnt deliberately left outstanding.
#define BAR_LGKM()  do {                                            \
    asm volatile("s_waitcnt lgkmcnt(0)" ::: "memory");              \
    __builtin_amdgcn_s_barrier();                                   \
} while (0)

__global__ __launch_bounds__(256, 4) void attn(
        const float* __restrict__ qg, const float* __restrict__ kg,
        const float* __restrict__ vg,
        const float* __restrict__ rph, const float* __restrict__ rpw,
        float* __restrict__ outg) {
    __shared__ float RelH[64 * 34];
    __shared__ float MH[4 * 64];
    __shared__ __align__(16) char arena[27136];
    float*  Ql   = (float*)arena;                 // phase0: 64*68*4 = 17408 B
    float*  RelW = (float*)(arena + 17408);       // phase0: 64*34*4 =  8704 B
    __bf16* Kl = (__bf16*)arena;                  // phase1: 64*72*2 = 9216 B
    __bf16* Vl = Kl + 64 * 72;                    // phase1: 64*68*2 = 8704 B
    __bf16* Pl = Vl + 64 * 68;                    // phase1: 4*16*72*2 = 9216 B

    const int tid  = threadIdx.x;
    const int w    = tid >> 6, lane = tid & 63;
    const int quad = lane >> 4, n16 = lane & 15;

    // ---- XCD head-affinity swizzle: idx -> (hp, bh) with bh%8 == idx%8 ----
    const int idx = blockIdx.x;           // 0..1023, launch-linear
    const int c   = idx & 7;              // assumed XCD (round-robin dispatch)
    const int r_  = idx >> 3;             // 0..127
    const int hp  = r_ & 15;
    const int bh  = c + ((r_ >> 4) << 3); // head-batch: all 16 hp of a head on one XCD

    const int bb = bh >> 4, nh = bh & 15;
    const int h0 = hp << 1;
    const int base = bb * 1048576 + nh * 64;   // per-head element base
    const int sq0  = h0 * 32;                  // first query row of block

    // ---- stage Q rows (fp32) into LDS, coalesced b128 ----
    {
        int r0 = tid >> 4, c0 = (tid & 15) << 2;
#pragma unroll
        for (int k = 0; k < 4; ++k) {
            int row = k * 16 + r0;
            f32x4 v = *(const f32x4*)(qg + base + (sq0 + row) * 1024 + c0);
            *(f32x4*)&Ql[row * 68 + c0] = v;
        }
    }
    __syncthreads();

    // ---- phase 0: rel tables (x log2e) + per-slot max ----
    {
        int ql = tid & 63, slot = tid >> 6;
        int isw = slot >> 1, khb = (slot & 1) << 4;
        int hh = h0 + (ql >> 5), wl = ql & 31;
        int row0 = (isw ? wl : hh) + 31 - khb;      // row_j = row0 - j
        const float* tp = (isw ? rpw : rph) + row0 * 64;
        const float* qrow = &Ql[ql * 68];
        float acc[16];
#pragma unroll
        for (int j = 0; j < 16; ++j) acc[j] = 0.f;
#pragma unroll 4
        for (int cq = 0; cq < 16; ++cq) {
            f32x4 qv = *(const f32x4*)(qrow + cq * 4);
#pragma unroll
            for (int j = 0; j < 16; ++j) {
                f32x4 tv = *(const f32x4*)(tp - j * 64 + cq * 4);
                acc[j] += qv.x * tv.x + qv.y * tv.y + qv.z * tv.z + qv.w * tv.w;
            }
        }
        float* dst = (isw ? RelW : RelH) + ql * 34 + khb;
        float hmax = -1e30f;
#pragma unroll
        for (int j = 0; j < 16; ++j) {
            float v = acc[j] * LOG2E;
            dst[j] = v;
            hmax = fmaxf(hmax, v);
        }
        MH[slot * 64 + ql] = hmax;
    }

    // ---- Q A-fragments from Ql: A[m=n16][k=quad*8+j], query = w*16+n16 ----
    const int qla = w * 16 + n16;
    bf16x8 qf[2];
#pragma unroll
    for (int ch = 0; ch < 2; ++ch) {
        const float* qp = &Ql[qla * 68 + ch * 32 + quad * 8];
        f32x4 a = ((const f32x4*)qp)[0];
        f32x4 b = ((const f32x4*)qp)[1];
        bf16x8 t;
        t[0] = (__bf16)a.x; t[1] = (__bf16)a.y; t[2] = (__bf16)a.z; t[3] = (__bf16)a.w;
        t[4] = (__bf16)b.x; t[5] = (__bf16)b.y; t[6] = (__bf16)b.z; t[7] = (__bf16)b.w;
        qf[ch] = t;
    }
    __syncthreads();   // phase-0 writes visible; Ql consumed into qf

    // C/D rows this lane owns: local query = w*16 + quad*4 + r
    int qlr[4];
#pragma unroll
    for (int r = 0; r < 4; ++r) qlr[r] = w * 16 + quad * 4 + r;

    // per-row static max M and (rel_w - M); rel_w is tile-invariant.
    // RelW consumed into registers here; the loop's first BAR_LGKM guarantees
    // these reads completed before Kl/Vl overwrite the aliased region.
    float rwm[4][2];
#pragma unroll
    for (int r = 0; r < 4; ++r) {
        int q = qlr[r];
        float M = fmaxf(MH[q], MH[64 + q]) + fmaxf(MH[128 + q], MH[192 + q]);
        rwm[r][0] = RelW[q * 34 + n16] - M;
        rwm[r][1] = RelW[q * 34 + 16 + n16] - M;
    }

    float lr[4] = {0.f, 0.f, 0.f, 0.f};
    f32x4 oc[4];
#pragma unroll
    for (int i = 0; i < 4; ++i) oc[i] = (f32x4){0.f, 0.f, 0.f, 0.f};

    const int krow = tid >> 3, kc0 = (tid & 7) << 3;   // K staging coords
    const int vc = tid & 63, vk0 = (tid >> 6) << 4;    // V staging coords
    const int pw = w * 1152;                           // per-wave P base

    // ---- register prefetch of tile 0 (in flight across the first barrier) ----
    f32x4 ka[2], kb[2];
    float vv[16];
#pragma unroll
    for (int half = 0; half < 2; ++half) {
        const float* kp = kg + base + (krow + half * 32) * 1024 + kc0;
        ka[half] = ((const f32x4*)kp)[0];
        kb[half] = ((const f32x4*)kp)[1];
    }
#pragma unroll
    for (int j = 0; j < 16; ++j)
        vv[j] = vg[base + (vk0 + j) * 1024 + vc];

    for (int kt = 0; kt < 16; ++kt) {
        // barrier A: previous iter's LDS reads all data-consumed; safe to
        // overwrite Kl/Vl/Pl. vmcnt stays outstanding (prefetch in flight).
        BAR_LGKM();

        // ---- store prefetched K tile (bf16, b128 writes) ----
#pragma unroll
        for (int half = 0; half < 2; ++half) {
            bf16x8 t;
            t[0] = (__bf16)ka[half].x; t[1] = (__bf16)ka[half].y;
            t[2] = (__bf16)ka[half].z; t[3] = (__bf16)ka[half].w;
            t[4] = (__bf16)kb[half].x; t[5] = (__bf16)kb[half].y;
            t[6] = (__bf16)kb[half].z; t[7] = (__bf16)kb[half].w;
            *(bf16x8*)&Kl[(krow + half * 32) * 72 + kc0] = t;
        }
        // ---- store prefetched V transposed: Vl[c][kk], packed pairs ----
#pragma unroll
        for (int j = 0; j < 8; ++j) {
            bf16x2 p; p[0] = (__bf16)vv[2 * j]; p[1] = (__bf16)vv[2 * j + 1];
            *(bf16x2*)&Vl[vc * 68 + vk0 + 2 * j] = p;
        }

        // ---- issue global loads for tile (kt+1)&15 before barrier B so they
        //      fly during the barrier wait + compute (consumed next iter) ----
        {
            const int ktn = (kt + 1) & 15;
#pragma unroll
            for (int half = 0; half < 2; ++half) {
                const float* kp = kg + base + (ktn * 64 + krow + half * 32) * 1024 + kc0;
                ka[half] = ((const f32x4*)kp)[0];
                kb[half] = ((const f32x4*)kp)[1];
            }
#pragma unroll
            for (int j = 0; j < 16; ++j)
                vv[j] = vg[base + (ktn * 64 + vk0 + j) * 1024 + vc];
        }

        // barrier B: staged Kl/Vl visible to all waves (lgkmcnt(0) covers the
        // ds_writes); the just-issued global loads remain outstanding.
        BAR_LGKM();

        float rh[4][2];
#pragma unroll
        for (int r = 0; r < 4; ++r) {
            float2 t = *(const float2*)&RelH[qlr[r] * 34 + kt * 2];
            rh[r][0] = t.x; rh[r][1] = t.y;
        }

        // ---- S = Q K^T : 8 MFMAs ----
        f32x4 s[4];
#pragma unroll
        for (int g = 0; g < 4; ++g) s[g] = (f32x4){0.f, 0.f, 0.f, 0.f};
#pragma unroll
        for (int ch = 0; ch < 2; ++ch)
#pragma unroll
            for (int g = 0; g < 4; ++g) {
                bf16x8 kf = *(const bf16x8*)&Kl[(g * 16 + n16) * 72 + ch * 32 + quad * 8];
                s[g] = __builtin_amdgcn_mfma_f32_16x16x32_bf16(qf[ch], kf, s[g], 0, 0, 0);
            }

        // ---- static-max softmax: p = exp2(s*SCALE2 + rh + rw - M) ----
#pragma unroll
        for (int r = 0; r < 4; ++r) {
            float p0 = __builtin_amdgcn_exp2f(fmaf(s[0][r], SCALE2, rh[r][0] + rwm[r][0]));
            float p1 = __builtin_amdgcn_exp2f(fmaf(s[1][r], SCALE2, rh[r][0] + rwm[r][1]));
            float p2 = __builtin_amdgcn_exp2f(fmaf(s[2][r], SCALE2, rh[r][1] + rwm[r][0]));
            float p3 = __builtin_amdgcn_exp2f(fmaf(s[3][r], SCALE2, rh[r][1] + rwm[r][1]));
            lr[r] += (p0 + p1) + (p2 + p3);
            int pr = pw + (quad * 4 + r) * 72;
            Pl[pr + n16]      = (__bf16)p0;
            Pl[pr + 16 + n16] = (__bf16)p1;
            Pl[pr + 32 + n16] = (__bf16)p2;
            Pl[pr + 48 + n16] = (__bf16)p3;
        }

        // ---- O += P V ---- (Pl is per-wave; wave-internal lgkm ordering only)
#pragma unroll
        for (int ko = 0; ko < 2; ++ko) {
            bf16x8 pf = *(const bf16x8*)&Pl[pw + n16 * 72 + ko * 32 + quad * 8];
#pragma unroll
            for (int cn = 0; cn < 4; ++cn) {
                const __bf16* vp = &Vl[(cn * 16 + n16) * 68 + ko * 32 + quad * 8];
                bf16x4 a = *(const bf16x4*)vp;
                bf16x4 b = *(const bf16x4*)(vp + 4);
                bf16x8 vf;
                vf[0] = a[0]; vf[1] = a[1]; vf[2] = a[2]; vf[3] = a[3];
                vf[4] = b[0]; vf[5] = b[1]; vf[6] = b[2]; vf[7] = b[3];
                oc[cn] = __builtin_amdgcn_mfma_f32_16x16x32_bf16(pf, vf, oc[cn], 0, 0, 0);
            }
        }
    }

    // ---- epilogue: one l-reduction across the 16-lane row group, store ----
#pragma unroll
    for (int r = 0; r < 4; ++r) {
        float l = lr[r];
        l += __shfl_xor(l, 1);
        l += __shfl_xor(l, 2);
        l += __shfl_xor(l, 4);
        l += __shfl_xor(l, 8);
        float inv = 1.f / l;
        int ob = base + (sq0 + qlr[r]) * 1024 + n16;
        outg[ob]      = oc[0][r] * inv;
        outg[ob + 16] = oc[1][r] * inv;
        outg[ob + 32] = oc[2][r] * inv;
        outg[ob + 48] = oc[3][r] * inv;
    }
}

extern "C" void kernel_launch(void* const* d_in, const int* in_sizes, int n_in,
                              void* d_out, int out_size, void* d_ws, size_t ws_size,
                              hipStream_t stream) {
    (void)in_sizes; (void)n_in; (void)out_size; (void)d_ws; (void)ws_size;
    const float* q   = (const float*)d_in[0];
    const float* k   = (const float*)d_in[1];
    const float* v   = (const float*)d_in[2];
    const float* rph = (const float*)d_in[3];
    const float* rpw = (const float*)d_in[4];
    attn<<<dim3(1024), 256, 0, stream>>>(q, k, v, rph, rpw, (float*)d_out);
}

// Round 3
// 195.986 us; speedup vs baseline: 1.0456x; 1.0187x over previous
//
#include <hip/hip_runtime.h>

// RelScaleAttend: b=4, 16 heads, s=1024 (32x32 img), d=64. Single fused kernel.
// Block = (h-pair, bh): 64 queries, 4 waves x 16 queries. K-tile = 64 keys.
// Phase 0: exact fp32 rel tables (x log2e) + per-query max-bound M into LDS.
// Phase 1: flash loop, bf16 MFMA 16x16x32, fp32 accum, STATIC-max softmax.
//
// SWAPPED-OPERAND QK^T: s = mfma(kf, qf) computes S^T, so each lane holds a
// full query-row slice: lane(quad,n16) = S[key=g*16+quad*4+r][query=n16].
// A/B fragments of 16x16x32 have identical per-lane layouts, so kf/qf loads
// are unchanged. With the PV k-index mapping key(ko,j)=(2ko+(j>>2))*16+
// quad*4+(j&3), the PV A-fragment is exactly the lane's own 16 softmax values
// (zero cross-lane movement, zero LDS round-trip for P). The PV C-layout then
// lands queries back on w*16+quad*4+r == the natural output mapping.
// V fragments read the matching 4-key runs from col-major Vl.
//
// K/V for tile kt+1 prefetched into registers during tile kt's compute; loop
// barriers are raw s_barrier + lgkmcnt(0) only (no vmcnt drain).
// XCD head-affinity swizzle keeps each head's 16 blocks on one XCD (L2 reuse).
//
// LDS (35840 B -> 4 blocks/CU): RelH 64x34 f32 + MH[4][64]
//   arena: phase0  Ql 64x68 f32 [0,17408) | RelW 64x34 f32 [17408,26112)
//          phase1  Kl 64x72 bf16 [0,9216) | Vl col-major 64x68 bf16 [9216,17920)
//   RelW/Ql die at the loop's first barrier (consumed into registers).

#define SCALE2 0.18033688f   // 0.125 * log2(e)
#define LOG2E  1.44269504f

typedef float  f32x4  __attribute__((ext_vector_type(4)));
typedef __bf16 bf16x8 __attribute__((ext_vector_type(8)));
typedef __bf16 bf16x4 __attribute__((ext_vector_type(4)));

// Barrier with LDS-completion only; vmcnt deliberately left outstanding.
#define BAR_LGKM()  do {                                            \
    asm volatile("s_waitcnt lgkmcnt(0)" ::: "memory");              \
    __builtin_amdgcn_s_barrier();                                   \
} while (0)

__global__ __launch_bounds__(256, 4) void attn(
        const float* __restrict__ qg, const float* __restrict__ kg,
        const float* __restrict__ vg,
        const float* __restrict__ rph, const float* __restrict__ rpw,
        float* __restrict__ outg) {
    __shared__ float RelH[64 * 34];
    __shared__ float MH[4 * 64];
    __shared__ __align__(16) char arena[26112];
    float*  Ql   = (float*)arena;                 // phase0: 64*68*4 = 17408 B
    float*  RelW = (float*)(arena + 17408);       // phase0: 64*34*4 =  8704 B
    __bf16* Kl = (__bf16*)arena;                  // phase1: 64*72*2 = 9216 B
    __bf16* Vl = Kl + 64 * 72;                    // phase1: 64*68*2 = 8704 B (col-major)

    const int tid  = threadIdx.x;
    const int w    = tid >> 6, lane = tid & 63;
    const int quad = lane >> 4, n16 = lane & 15;

    // ---- XCD head-affinity swizzle ----
    const int idx = blockIdx.x;
    const int c   = idx & 7;
    const int r_  = idx >> 3;
    const int hp  = r_ & 15;
    const int bh  = c + ((r_ >> 4) << 3);

    const int bb = bh >> 4, nh = bh & 15;
    const int h0 = hp << 1;
    const int base = bb * 1048576 + nh * 64;   // per-head element base
    const int sq0  = h0 * 32;                  // first query row of block

    // ---- stage Q rows (fp32) into LDS, coalesced b128 ----
    {
        int r0 = tid >> 4, c0 = (tid & 15) << 2;
#pragma unroll
        for (int k = 0; k < 4; ++k) {
            int row = k * 16 + r0;
            f32x4 v = *(const f32x4*)(qg + base + (sq0 + row) * 1024 + c0);
            *(f32x4*)&Ql[row * 68 + c0] = v;
        }
    }
    __syncthreads();

    // ---- phase 0: rel tables (x log2e) + per-slot max ----
    {
        int ql = tid & 63, slot = tid >> 6;
        int isw = slot >> 1, khb = (slot & 1) << 4;
        int hh = h0 + (ql >> 5), wl = ql & 31;
        int row0 = (isw ? wl : hh) + 31 - khb;      // row_j = row0 - j
        const float* tp = (isw ? rpw : rph) + row0 * 64;
        const float* qrow = &Ql[ql * 68];
        float acc[16];
#pragma unroll
        for (int j = 0; j < 16; ++j) acc[j] = 0.f;
#pragma unroll 4
        for (int cq = 0; cq < 16; ++cq) {
            f32x4 qv = *(const f32x4*)(qrow + cq * 4);
#pragma unroll
            for (int j = 0; j < 16; ++j) {
                f32x4 tv = *(const f32x4*)(tp - j * 64 + cq * 4);
                acc[j] += qv.x * tv.x + qv.y * tv.y + qv.z * tv.z + qv.w * tv.w;
            }
        }
        float* dst = (isw ? RelW : RelH) + ql * 34 + khb;
        float hmax = -1e30f;
#pragma unroll
        for (int j = 0; j < 16; ++j) {
            float v = acc[j] * LOG2E;
            dst[j] = v;
            hmax = fmaxf(hmax, v);
        }
        MH[slot * 64 + ql] = hmax;
    }

    // ---- Q fragments (works as MFMA B-operand): lane holds Q[w*16+n16][quad*8+j]
    const int qn = w * 16 + n16;             // this lane's softmax query
    bf16x8 qf[2];
#pragma unroll
    for (int ch = 0; ch < 2; ++ch) {
        const float* qp = &Ql[qn * 68 + ch * 32 + quad * 8];
        f32x4 a = ((const f32x4*)qp)[0];
        f32x4 b = ((const f32x4*)qp)[1];
        bf16x8 t;
        t[0] = (__bf16)a.x; t[1] = (__bf16)a.y; t[2] = (__bf16)a.z; t[3] = (__bf16)a.w;
        t[4] = (__bf16)b.x; t[5] = (__bf16)b.y; t[6] = (__bf16)b.z; t[7] = (__bf16)b.w;
        qf[ch] = t;
    }
    __syncthreads();   // phase-0 writes visible; Ql consumed into qf

    // ---- per-lane static max M and rwm2[i][r] = RelW[qn][i*16+quad*4+r] - M
    float rwm2[2][4];
    {
        float M = fmaxf(MH[qn], MH[64 + qn]) + fmaxf(MH[128 + qn], MH[192 + qn]);
#pragma unroll
        for (int i = 0; i < 2; ++i) {
            float2 u = *(const float2*)&RelW[qn * 34 + i * 16 + quad * 4];
            float2 v2 = *(const float2*)&RelW[qn * 34 + i * 16 + quad * 4 + 2];
            rwm2[i][0] = u.x - M;  rwm2[i][1] = u.y - M;
            rwm2[i][2] = v2.x - M; rwm2[i][3] = v2.y - M;
        }
    }

    float lr = 0.f;
    f32x4 oc[4];
#pragma unroll
    for (int i = 0; i < 4; ++i) oc[i] = (f32x4){0.f, 0.f, 0.f, 0.f};

    const int krow = tid >> 3, kc0 = (tid & 7) << 3;   // K staging coords
    const int vc = tid & 63, vk0 = (tid >> 6) << 4;    // V staging coords

    // ---- register prefetch of tile 0 (in flight across the first barrier) ----
    f32x4 ka[2], kb[2];
    float vv[16];
#pragma unroll
    for (int half = 0; half < 2; ++half) {
        const float* kp = kg + base + (krow + half * 32) * 1024 + kc0;
        ka[half] = ((const f32x4*)kp)[0];
        kb[half] = ((const f32x4*)kp)[1];
    }
#pragma unroll
    for (int j = 0; j < 16; ++j)
        vv[j] = vg[base + (vk0 + j) * 1024 + vc];

    for (int kt = 0; kt < 16; ++kt) {
        // barrier A: previous iter's LDS reads data-consumed; safe to overwrite.
        BAR_LGKM();

        // ---- store prefetched K tile (bf16, b128 writes) ----
#pragma unroll
        for (int half = 0; half < 2; ++half) {
            bf16x8 t;
            t[0] = (__bf16)ka[half].x; t[1] = (__bf16)ka[half].y;
            t[2] = (__bf16)ka[half].z; t[3] = (__bf16)ka[half].w;
            t[4] = (__bf16)kb[half].x; t[5] = (__bf16)kb[half].y;
            t[6] = (__bf16)kb[half].z; t[7] = (__bf16)kb[half].w;
            *(bf16x8*)&Kl[(krow + half * 32) * 72 + kc0] = t;
        }
        // ---- store prefetched V col-major: Vl[col][key], b64 packed ----
#pragma unroll
        for (int m = 0; m < 4; ++m) {
            bf16x4 p;
            p[0] = (__bf16)vv[4 * m];     p[1] = (__bf16)vv[4 * m + 1];
            p[2] = (__bf16)vv[4 * m + 2]; p[3] = (__bf16)vv[4 * m + 3];
            *(bf16x4*)&Vl[vc * 68 + vk0 + 4 * m] = p;
        }

        // ---- issue global loads for tile (kt+1)&15 (fly across barrier B) ----
        {
            const int ktn = (kt + 1) & 15;
#pragma unroll
            for (int half = 0; half < 2; ++half) {
                const float* kp = kg + base + (ktn * 64 + krow + half * 32) * 1024 + kc0;
                ka[half] = ((const f32x4*)kp)[0];
                kb[half] = ((const f32x4*)kp)[1];
            }
#pragma unroll
            for (int j = 0; j < 16; ++j)
                vv[j] = vg[base + (ktn * 64 + vk0 + j) * 1024 + vc];
        }

        // barrier B: staged Kl/Vl visible (lgkmcnt(0) covers ds_writes).
        BAR_LGKM();

        // ---- S^T = K Q^T : 8 MFMAs (swapped operands, same fragment loads) ----
        // s[g][r] = S[key = g*16 + quad*4 + r][query = qn]
        f32x4 s[4];
#pragma unroll
        for (int g = 0; g < 4; ++g) s[g] = (f32x4){0.f, 0.f, 0.f, 0.f};
#pragma unroll
        for (int ch = 0; ch < 2; ++ch)
#pragma unroll
            for (int g = 0; g < 4; ++g) {
                bf16x8 kf = *(const bf16x8*)&Kl[(g * 16 + n16) * 72 + ch * 32 + quad * 8];
                s[g] = __builtin_amdgcn_mfma_f32_16x16x32_bf16(kf, qf[ch], s[g], 0, 0, 0);
            }

        // ---- static-max softmax, fully per-lane (query = qn fixed) ----
        // key = g*16 + quad*4 + r; kh = kt*2 + (g>=2); kw = (g&1)*16 + quad*4 + r
        const float2 rhp = *(const float2*)&RelH[qn * 34 + kt * 2];
        float p[4][4];
#pragma unroll
        for (int g = 0; g < 4; ++g) {
            const float rbase = (g >= 2) ? rhp.y : rhp.x;
#pragma unroll
            for (int r = 0; r < 4; ++r)
                p[g][r] = __builtin_amdgcn_exp2f(fmaf(s[g][r], SCALE2, rbase + rwm2[g & 1][r]));
        }
#pragma unroll
        for (int g = 0; g < 4; ++g)
            lr += ((p[g][0] + p[g][1]) + (p[g][2] + p[g][3]));

        // ---- PV A-fragments: the lane's own p values, packed (zero shuffle) ----
        // k = quad*8 + j  <->  key = (2ko + (j>>2))*16 + quad*4 + (j&3)
        bf16x8 pf[2];
#pragma unroll
        for (int ko = 0; ko < 2; ++ko) {
            bf16x8 t;
            t[0] = (__bf16)p[2 * ko][0];     t[1] = (__bf16)p[2 * ko][1];
            t[2] = (__bf16)p[2 * ko][2];     t[3] = (__bf16)p[2 * ko][3];
            t[4] = (__bf16)p[2 * ko + 1][0]; t[5] = (__bf16)p[2 * ko + 1][1];
            t[6] = (__bf16)p[2 * ko + 1][2]; t[7] = (__bf16)p[2 * ko + 1][3];
            pf[ko] = t;
        }

        // ---- O += P V : B-fragment = V[key(ko,k)][cn*16+n16] from col-major Vl
#pragma unroll
        for (int ko = 0; ko < 2; ++ko)
#pragma unroll
            for (int cn = 0; cn < 4; ++cn) {
                const __bf16* vp = &Vl[(cn * 16 + n16) * 68 + ko * 32 + quad * 4];
                bf16x4 a = *(const bf16x4*)vp;        // keys 2ko*16 + quad*4 + 0..3
                bf16x4 b = *(const bf16x4*)(vp + 16); // keys (2ko+1)*16 + quad*4 + 0..3
                bf16x8 vf;
                vf[0] = a[0]; vf[1] = a[1]; vf[2] = a[2]; vf[3] = a[3];
                vf[4] = b[0]; vf[5] = b[1]; vf[6] = b[2]; vf[7] = b[3];
                oc[cn] = __builtin_amdgcn_mfma_f32_16x16x32_bf16(pf[ko], vf, oc[cn], 0, 0, 0);
            }
    }

    // ---- epilogue: full row-sum per query, redistribute, store ----
    // After xor-reduce over quads, every lane holds L[query = n16].
    lr += __shfl_xor(lr, 16);
    lr += __shfl_xor(lr, 32);
    float linv[4];
#pragma unroll
    for (int r = 0; r < 4; ++r)
        linv[r] = 1.f / __shfl(lr, quad * 4 + r, 64);   // L[query = quad*4+r]

    // oc[cn][r] = O[query = w*16 + quad*4 + r][dim = cn*16 + n16]
#pragma unroll
    for (int r = 0; r < 4; ++r) {
        int ob = base + (sq0 + w * 16 + quad * 4 + r) * 1024 + n16;
        outg[ob]      = oc[0][r] * linv[r];
        outg[ob + 16] = oc[1][r] * linv[r];
        outg[ob + 32] = oc[2][r] * linv[r];
        outg[ob + 48] = oc[3][r] * linv[r];
    }
}

extern "C" void kernel_launch(void* const* d_in, const int* in_sizes, int n_in,
                              void* d_out, int out_size, void* d_ws, size_t ws_size,
                              hipStream_t stream) {
    (void)in_sizes; (void)n_in; (void)out_size; (void)d_ws; (void)ws_size;
    const float* q   = (const float*)d_in[0];
    const float* k   = (const float*)d_in[1];
    const float* v   = (const float*)d_in[2];
    const float* rph = (const float*)d_in[3];
    const float* rpw = (const float*)d_in[4];
    attn<<<dim3(1024), 256, 0, stream>>>(q, k, v, rph, rpw, (float*)d_out);
}

// Round 4
// 194.729 us; speedup vs baseline: 1.0523x; 1.0065x over previous
//
#include <hip/hip_runtime.h>

// RelScaleAttend: b=4, 16 heads, s=1024 (32x32 img), d=64. Single fused kernel.
// Block = (h-pair, bh): 64 queries, 4 waves x 16 queries. K-tile = 128 keys
// (KVBLK=128: 8 loop iterations x 2 barriers -- phase-count halved vs KVBLK=64,
// testing the "per-phase overhead dominates" theory from rounds 1-3 where time
// was invariant to large instruction-count changes).
//
// Phase 0: exact fp32 rel tables (x log2e) + per-query max-bound M into LDS.
// Phase 1: flash loop, bf16 MFMA 16x16x32, fp32 accum, STATIC-max softmax:
//   p = exp2(qk*SCALE2 + relh2 + relw2 - M[q]); M = max_kh relh2 + max_kw relw2
//
// SWAPPED-OPERAND QK^T: s = mfma(kf, qf) computes S^T; lane(quad,n16) holds
// S[key = g*16+quad*4+r][query = qn], g = 0..7 over the 128-key tile. The PV
// A-fragment is then exactly the lane's own 32 softmax values (zero cross-lane
// movement); kh = kt*4 + (g>>1), kw = (g&1)*16 + quad*4 + r.
//
// K/V for tile kt+1 prefetched into registers during tile kt's compute; loop
// barriers are raw s_barrier + lgkmcnt(0) only (no vmcnt drain).
// XCD head-affinity swizzle keeps each head's 16 blocks on one XCD (L2 reuse).
//
// LDS (45568 B -> 3 blocks/CU): RelH 64x36 f32 (stride 36 => aligned f32x4 rh
// reads) + MH[4][64];
//   arena: phase0  Ql 64x68 f32 [0,17408) | RelW 64x34 f32 [17408,26112)
//          phase1  Kl 128x72 bf16 [0,18432) | Vl col-major 64x132 bf16 [18432,35328)
//   RelW/Ql die at the loop's first barrier (consumed into registers).

#define SCALE2 0.18033688f   // 0.125 * log2(e)
#define LOG2E  1.44269504f

typedef float  f32x4  __attribute__((ext_vector_type(4)));
typedef __bf16 bf16x8 __attribute__((ext_vector_type(8)));
typedef __bf16 bf16x4 __attribute__((ext_vector_type(4)));

// Barrier with LDS-completion only; vmcnt deliberately left outstanding.
#define BAR_LGKM()  do {                                            \
    asm volatile("s_waitcnt lgkmcnt(0)" ::: "memory");              \
    __builtin_amdgcn_s_barrier();                                   \
} while (0)

__global__ __launch_bounds__(256, 3) void attn(
        const float* __restrict__ qg, const float* __restrict__ kg,
        const float* __restrict__ vg,
        const float* __restrict__ rph, const float* __restrict__ rpw,
        float* __restrict__ outg) {
    __shared__ float RelH[64 * 36];
    __shared__ float MH[4 * 64];
    __shared__ __align__(16) char arena[35328];
    float*  Ql   = (float*)arena;                 // phase0: 64*68*4 = 17408 B
    float*  RelW = (float*)(arena + 17408);       // phase0: 64*34*4 =  8704 B
    __bf16* Kl = (__bf16*)arena;                  // phase1: 128*72*2 = 18432 B
    __bf16* Vl = Kl + 128 * 72;                   // phase1: 64*132*2 = 16896 B (col-major)

    const int tid  = threadIdx.x;
    const int w    = tid >> 6, lane = tid & 63;
    const int quad = lane >> 4, n16 = lane & 15;

    // ---- XCD head-affinity swizzle ----
    const int idx = blockIdx.x;
    const int c   = idx & 7;
    const int r_  = idx >> 3;
    const int hp  = r_ & 15;
    const int bh  = c + ((r_ >> 4) << 3);

    const int bb = bh >> 4, nh = bh & 15;
    const int h0 = hp << 1;
    const int base = bb * 1048576 + nh * 64;   // per-head element base
    const int sq0  = h0 * 32;                  // first query row of block

    // ---- stage Q rows (fp32) into LDS, coalesced b128 ----
    {
        int r0 = tid >> 4, c0 = (tid & 15) << 2;
#pragma unroll
        for (int k = 0; k < 4; ++k) {
            int row = k * 16 + r0;
            f32x4 v = *(const f32x4*)(qg + base + (sq0 + row) * 1024 + c0);
            *(f32x4*)&Ql[row * 68 + c0] = v;
        }
    }
    __syncthreads();

    // ---- phase 0: rel tables (x log2e) + per-slot max ----
    {
        int ql = tid & 63, slot = tid >> 6;
        int isw = slot >> 1, khb = (slot & 1) << 4;
        int hh = h0 + (ql >> 5), wl = ql & 31;
        int row0 = (isw ? wl : hh) + 31 - khb;      // row_j = row0 - j
        const float* tp = (isw ? rpw : rph) + row0 * 64;
        const float* qrow = &Ql[ql * 68];
        float acc[16];
#pragma unroll
        for (int j = 0; j < 16; ++j) acc[j] = 0.f;
#pragma unroll 4
        for (int cq = 0; cq < 16; ++cq) {
            f32x4 qv = *(const f32x4*)(qrow + cq * 4);
#pragma unroll
            for (int j = 0; j < 16; ++j) {
                f32x4 tv = *(const f32x4*)(tp - j * 64 + cq * 4);
                acc[j] += qv.x * tv.x + qv.y * tv.y + qv.z * tv.z + qv.w * tv.w;
            }
        }
        float* dst = isw ? (RelW + ql * 34 + khb) : (RelH + ql * 36 + khb);
        float hmax = -1e30f;
#pragma unroll
        for (int j = 0; j < 16; ++j) {
            float v = acc[j] * LOG2E;
            dst[j] = v;
            hmax = fmaxf(hmax, v);
        }
        MH[slot * 64 + ql] = hmax;
    }

    // ---- Q fragments (MFMA B-operand): lane holds Q[w*16+n16][quad*8+j]
    const int qn = w * 16 + n16;             // this lane's softmax query
    bf16x8 qf[2];
#pragma unroll
    for (int ch = 0; ch < 2; ++ch) {
        const float* qp = &Ql[qn * 68 + ch * 32 + quad * 8];
        f32x4 a = ((const f32x4*)qp)[0];
        f32x4 b = ((const f32x4*)qp)[1];
        bf16x8 t;
        t[0] = (__bf16)a.x; t[1] = (__bf16)a.y; t[2] = (__bf16)a.z; t[3] = (__bf16)a.w;
        t[4] = (__bf16)b.x; t[5] = (__bf16)b.y; t[6] = (__bf16)b.z; t[7] = (__bf16)b.w;
        qf[ch] = t;
    }
    __syncthreads();   // phase-0 writes visible; Ql consumed into qf

    // ---- per-lane static max M and rwm2[i][r] = RelW[qn][i*16+quad*4+r] - M
    float rwm2[2][4];
    {
        float M = fmaxf(MH[qn], MH[64 + qn]) + fmaxf(MH[128 + qn], MH[192 + qn]);
#pragma unroll
        for (int i = 0; i < 2; ++i) {
            float2 u = *(const float2*)&RelW[qn * 34 + i * 16 + quad * 4];
            float2 v2 = *(const float2*)&RelW[qn * 34 + i * 16 + quad * 4 + 2];
            rwm2[i][0] = u.x - M;  rwm2[i][1] = u.y - M;
            rwm2[i][2] = v2.x - M; rwm2[i][3] = v2.y - M;
        }
    }

    float lr = 0.f;
    f32x4 oc[4];
#pragma unroll
    for (int i = 0; i < 4; ++i) oc[i] = (f32x4){0.f, 0.f, 0.f, 0.f};

    const int krow = tid >> 3, kc0 = (tid & 7) << 3;   // K staging coords
    const int vc = tid & 63, vk0 = (tid >> 6) << 5;    // V staging: 32 keys/wave

    // ---- register prefetch of tile 0 (in flight across the first barrier) ----
    f32x4 ka[4], kb[4];
    float vv[32];
#pragma unroll
    for (int h = 0; h < 4; ++h) {
        const float* kp = kg + base + (krow + h * 32) * 1024 + kc0;
        ka[h] = ((const f32x4*)kp)[0];
        kb[h] = ((const f32x4*)kp)[1];
    }
#pragma unroll
    for (int j = 0; j < 32; ++j)
        vv[j] = vg[base + (vk0 + j) * 1024 + vc];

    for (int kt = 0; kt < 8; ++kt) {
        // barrier A: previous iter's LDS reads data-consumed; safe to overwrite.
        BAR_LGKM();

        // ---- store prefetched K tile (bf16, b128 writes) ----
#pragma unroll
        for (int h = 0; h < 4; ++h) {
            bf16x8 t;
            t[0] = (__bf16)ka[h].x; t[1] = (__bf16)ka[h].y;
            t[2] = (__bf16)ka[h].z; t[3] = (__bf16)ka[h].w;
            t[4] = (__bf16)kb[h].x; t[5] = (__bf16)kb[h].y;
            t[6] = (__bf16)kb[h].z; t[7] = (__bf16)kb[h].w;
            *(bf16x8*)&Kl[(krow + h * 32) * 72 + kc0] = t;
        }
        // ---- store prefetched V col-major: Vl[col][key], b64 packed ----
#pragma unroll
        for (int m = 0; m < 8; ++m) {
            bf16x4 p;
            p[0] = (__bf16)vv[4 * m];     p[1] = (__bf16)vv[4 * m + 1];
            p[2] = (__bf16)vv[4 * m + 2]; p[3] = (__bf16)vv[4 * m + 3];
            *(bf16x4*)&Vl[vc * 132 + vk0 + 4 * m] = p;
        }

        // ---- issue global loads for tile (kt+1)&7 (fly across barrier B) ----
        {
            const int ktn = (kt + 1) & 7;
#pragma unroll
            for (int h = 0; h < 4; ++h) {
                const float* kp = kg + base + (ktn * 128 + krow + h * 32) * 1024 + kc0;
                ka[h] = ((const f32x4*)kp)[0];
                kb[h] = ((const f32x4*)kp)[1];
            }
#pragma unroll
            for (int j = 0; j < 32; ++j)
                vv[j] = vg[base + (ktn * 128 + vk0 + j) * 1024 + vc];
        }

        // barrier B: staged Kl/Vl visible (lgkmcnt(0) covers ds_writes).
        BAR_LGKM();

        // ---- S^T = K Q^T : 16 MFMAs (swapped operands) ----
        // s[g][r] = S[key = g*16 + quad*4 + r][query = qn], g = 0..7
        f32x4 s[8];
#pragma unroll
        for (int g = 0; g < 8; ++g) s[g] = (f32x4){0.f, 0.f, 0.f, 0.f};
#pragma unroll
        for (int ch = 0; ch < 2; ++ch)
#pragma unroll
            for (int g = 0; g < 8; ++g) {
                bf16x8 kf = *(const bf16x8*)&Kl[(g * 16 + n16) * 72 + ch * 32 + quad * 8];
                s[g] = __builtin_amdgcn_mfma_f32_16x16x32_bf16(kf, qf[ch], s[g], 0, 0, 0);
            }

        // ---- static-max softmax, fully per-lane (query = qn fixed) ----
        // kh = kt*4 + (g>>1); kw = (g&1)*16 + quad*4 + r
        const f32x4 rhv = *(const f32x4*)&RelH[qn * 36 + kt * 4];
        float p[8][4];
#pragma unroll
        for (int g = 0; g < 8; ++g) {
            const float rbase = rhv[g >> 1];
#pragma unroll
            for (int r = 0; r < 4; ++r)
                p[g][r] = __builtin_amdgcn_exp2f(fmaf(s[g][r], SCALE2, rbase + rwm2[g & 1][r]));
        }
#pragma unroll
        for (int g = 0; g < 8; ++g)
            lr += ((p[g][0] + p[g][1]) + (p[g][2] + p[g][3]));

        // ---- PV A-fragments: lane's own p values, packed (zero shuffle) ----
        // k = quad*8 + j  <->  key = (2ko + (j>>2))*16 + quad*4 + (j&3)
        bf16x8 pf[4];
#pragma unroll
        for (int ko = 0; ko < 4; ++ko) {
            bf16x8 t;
            t[0] = (__bf16)p[2 * ko][0];     t[1] = (__bf16)p[2 * ko][1];
            t[2] = (__bf16)p[2 * ko][2];     t[3] = (__bf16)p[2 * ko][3];
            t[4] = (__bf16)p[2 * ko + 1][0]; t[5] = (__bf16)p[2 * ko + 1][1];
            t[6] = (__bf16)p[2 * ko + 1][2]; t[7] = (__bf16)p[2 * ko + 1][3];
            pf[ko] = t;
        }

        // ---- O += P V : B-fragment = V[key(ko,k)][cn*16+n16] from col-major Vl
#pragma unroll
        for (int ko = 0; ko < 4; ++ko)
#pragma unroll
            for (int cn = 0; cn < 4; ++cn) {
                const __bf16* vp = &Vl[(cn * 16 + n16) * 132 + ko * 32 + quad * 4];
                bf16x4 a = *(const bf16x4*)vp;        // keys 2ko*16 + quad*4 + 0..3
                bf16x4 b = *(const bf16x4*)(vp + 16); // keys (2ko+1)*16 + quad*4 + 0..3
                bf16x8 vf;
                vf[0] = a[0]; vf[1] = a[1]; vf[2] = a[2]; vf[3] = a[3];
                vf[4] = b[0]; vf[5] = b[1]; vf[6] = b[2]; vf[7] = b[3];
                oc[cn] = __builtin_amdgcn_mfma_f32_16x16x32_bf16(pf[ko], vf, oc[cn], 0, 0, 0);
            }
    }

    // ---- epilogue: full row-sum per query, redistribute, store ----
    lr += __shfl_xor(lr, 16);
    lr += __shfl_xor(lr, 32);
    float linv[4];
#pragma unroll
    for (int r = 0; r < 4; ++r)
        linv[r] = 1.f / __shfl(lr, quad * 4 + r, 64);   // L[query = quad*4+r]

    // oc[cn][r] = O[query = w*16 + quad*4 + r][dim = cn*16 + n16]
#pragma unroll
    for (int r = 0; r < 4; ++r) {
        int ob = base + (sq0 + w * 16 + quad * 4 + r) * 1024 + n16;
        outg[ob]      = oc[0][r] * linv[r];
        outg[ob + 16] = oc[1][r] * linv[r];
        outg[ob + 32] = oc[2][r] * linv[r];
        outg[ob + 48] = oc[3][r] * linv[r];
    }
}

extern "C" void kernel_launch(void* const* d_in, const int* in_sizes, int n_in,
                              void* d_out, int out_size, void* d_ws, size_t ws_size,
                              hipStream_t stream) {
    (void)in_sizes; (void)n_in; (void)out_size; (void)d_ws; (void)ws_size;
    const float* q   = (const float*)d_in[0];
    const float* k   = (const float*)d_in[1];
    const float* v   = (const float*)d_in[2];
    const float* rph = (const float*)d_in[3];
    const float* rpw = (const float*)d_in[4];
    attn<<<dim3(1024), 256, 0, stream>>>(q, k, v, rph, rpw, (float*)d_out);
}